// Round 1
// baseline (1728.954 us; speedup 1.0000x reference)
//
#include <hip/hip_runtime.h>

#define N_NODES 100000
#define N_EDGES 1600000
#define D_IN 256
#define D_OUT 128

// ---------------------------------------------------------------------------
// Kernel 1: out[n][c] = b[c]  (bias broadcast init; out is re-poisoned 0xAA
// before every timed launch, so we must fully initialize it)
// ---------------------------------------------------------------------------
__global__ void init_out_kernel(float* __restrict__ out,
                                const float* __restrict__ b) {
    int idx = blockIdx.x * blockDim.x + threadIdx.x;   // over N*D_OUT/4
    const int total = N_NODES * (D_OUT / 4);
    if (idx >= total) return;
    int c4 = idx & (D_OUT / 4 - 1);                    // 32 float4 per row
    float4 bv = ((const float4*)b)[c4];
    ((float4*)out)[idx] = bv;
}

// ---------------------------------------------------------------------------
// Kernel 2: support = x @ W   (f32 vector GEMM)
// One wave handles 16 rows; lane handles cols [2*lane, 2*lane+1].
// x values are wave-uniform broadcast loads; W rows are coalesced float2.
// W (131 KB) stays L2-resident; reuse across 16 rows amortizes W traffic.
// ---------------------------------------------------------------------------
#define ROWS_PER_WAVE 16

__global__ __launch_bounds__(256) void gemm_xw_kernel(
        const float* __restrict__ x,
        const float* __restrict__ W,
        float* __restrict__ support) {
    int wave = (int)((blockIdx.x * blockDim.x + threadIdx.x) >> 6);
    int lane = threadIdx.x & 63;
    int row0 = wave * ROWS_PER_WAVE;
    if (row0 >= N_NODES) return;

    float2 acc[ROWS_PER_WAVE];
#pragma unroll
    for (int r = 0; r < ROWS_PER_WAVE; ++r) acc[r] = make_float2(0.f, 0.f);

    const float2* Wp = (const float2*)W;   // W[k][c] -> float2 index k*64+lane

    for (int k4 = 0; k4 < D_IN / 4; ++k4) {
        float4 xv[ROWS_PER_WAVE];
#pragma unroll
        for (int r = 0; r < ROWS_PER_WAVE; ++r)
            xv[r] = *(const float4*)(x + (size_t)(row0 + r) * D_IN + k4 * 4);
        float2 w0 = Wp[(k4 * 4 + 0) * 64 + lane];
        float2 w1 = Wp[(k4 * 4 + 1) * 64 + lane];
        float2 w2 = Wp[(k4 * 4 + 2) * 64 + lane];
        float2 w3 = Wp[(k4 * 4 + 3) * 64 + lane];
#pragma unroll
        for (int r = 0; r < ROWS_PER_WAVE; ++r) {
            acc[r].x += xv[r].x * w0.x + xv[r].y * w1.x
                      + xv[r].z * w2.x + xv[r].w * w3.x;
            acc[r].y += xv[r].x * w0.y + xv[r].y * w1.y
                      + xv[r].z * w2.y + xv[r].w * w3.y;
        }
    }
#pragma unroll
    for (int r = 0; r < ROWS_PER_WAVE; ++r)
        *(float2*)(support + (size_t)(row0 + r) * D_OUT + 2 * lane) = acc[r];
}

// ---------------------------------------------------------------------------
// Kernel 3: scatter — one wave per edge, float2 (2 channels) per lane.
// out[dst] += w * support[src]   via hardware f32 atomics.
// ---------------------------------------------------------------------------
__global__ __launch_bounds__(256) void scatter_kernel(
        const float* __restrict__ support,
        const int* __restrict__ src,
        const int* __restrict__ dst,
        const float* __restrict__ ew,
        float* __restrict__ out) {
    int wid = (int)((blockIdx.x * blockDim.x + threadIdx.x) >> 6);
    int lane = threadIdx.x & 63;
    if (wid >= N_EDGES) return;
    int s = src[wid];
    int d = dst[wid];
    float wt = ew[wid];
    float2 v = *(const float2*)(support + (size_t)s * D_OUT + 2 * lane);
    float* op = out + (size_t)d * D_OUT + 2 * lane;
    unsafeAtomicAdd(op + 0, v.x * wt);
    unsafeAtomicAdd(op + 1, v.y * wt);
}

// ---------------------------------------------------------------------------
extern "C" void kernel_launch(void* const* d_in, const int* in_sizes, int n_in,
                              void* d_out, int out_size, void* d_ws, size_t ws_size,
                              hipStream_t stream) {
    const float* x   = (const float*)d_in[0];
    const int* esrc  = (const int*)d_in[1];
    const int* edst  = (const int*)d_in[2];
    const float* ew  = (const float*)d_in[3];
    const float* W   = (const float*)d_in[4];
    const float* b   = (const float*)d_in[5];
    float* out = (float*)d_out;

    float* support = (float*)d_ws;   // N_NODES * D_OUT floats = 51.2 MB

    // 1) out = b (broadcast)
    {
        int total = N_NODES * (D_OUT / 4);
        int blk = 256;
        int grid = (total + blk - 1) / blk;
        init_out_kernel<<<grid, blk, 0, stream>>>(out, b);
    }
    // 2) support = x @ W
    {
        int waves = (N_NODES + ROWS_PER_WAVE - 1) / ROWS_PER_WAVE;  // 6250
        int blk = 256;                                              // 4 waves
        int grid = (waves + 3) / 4;
        gemm_xw_kernel<<<grid, blk, 0, stream>>>(x, W, support);
    }
    // 3) out[dst] += w * support[src]
    {
        int blk = 256;                        // 4 edges per block
        int grid = (N_EDGES + 3) / 4;
        scatter_kernel<<<grid, blk, 0, stream>>>(support, esrc, edst, ew, out);
    }
}

// Round 2
// 532.985 us; speedup vs baseline: 3.2439x; 3.2439x over previous
//
#include <hip/hip_runtime.h>

#define N_NODES 100000
#define N_EDGES 1600000
#define D_IN 256
#define D_OUT 128

#define SCAN_BLK 256
#define N_SCAN_BLKS ((N_NODES + SCAN_BLK - 1) / SCAN_BLK)   // 391

typedef __attribute__((ext_vector_type(8))) short bf16x8;
typedef __attribute__((ext_vector_type(4))) float f32x4;

__device__ __forceinline__ unsigned short f2bf(float f) {
    unsigned u = __float_as_uint(f);
    u += 0x7FFF + ((u >> 16) & 1);          // round-to-nearest-even
    return (unsigned short)(u >> 16);
}

// ---------------------------------------------------------------------------
// W[256][128] f32  ->  Wt[128][256] bf16 (col-major W, so B-fragments are
// contiguous 16B loads)
// ---------------------------------------------------------------------------
__global__ void conv_w_kernel(const float* __restrict__ W,
                              unsigned short* __restrict__ Wt) {
    int idx = blockIdx.x * 256 + threadIdx.x;     // over 128*256 = 32768
    if (idx >= D_OUT * D_IN) return;
    int c = idx >> 8;          // 0..127
    int k = idx & 255;         // 0..255
    Wt[idx] = f2bf(W[(size_t)k * D_OUT + c]);
}

// ---------------------------------------------------------------------------
// support = x @ W via bf16 MFMA 16x16x32.
// One wave owns 16 rows x all 128 cols (8 col-tiles, acc = 8 x f32x4).
// A frag: lane l holds x[r0 + (l&15)][k0 + (l>>4)*8 + j], j=0..7 (f32->bf16).
// B frag: lane l holds W[k0 + (l>>4)*8 + j][t*16 + (l&15)] = Wt[col][k...]
// C:      lane l holds support[r0 + (l>>4)*4 + j][t*16 + (l&15)]
// No LDS, no barriers; Wt (64 KB) is L2-resident.
// ---------------------------------------------------------------------------
__global__ __launch_bounds__(256) void gemm_mfma_kernel(
        const float* __restrict__ x,
        const unsigned short* __restrict__ Wt,
        float* __restrict__ support) {
    int wid = (int)((blockIdx.x * blockDim.x + threadIdx.x) >> 6);
    int lane = threadIdx.x & 63;
    if (wid >= N_NODES / 16) return;        // 6250 waves exactly
    int r0 = wid * 16;
    int rowA = r0 + (lane & 15);
    int kgrp = (lane >> 4) * 8;             // 0,8,16,24

    f32x4 acc[8];
#pragma unroll
    for (int t = 0; t < 8; ++t) acc[t] = (f32x4){0.f, 0.f, 0.f, 0.f};

    const float* xrow = x + (size_t)rowA * D_IN + kgrp;
    int colbase = lane & 15;

#pragma unroll
    for (int ks = 0; ks < 8; ++ks) {
        int k0 = ks * 32;
        float4 a0 = *(const float4*)(xrow + k0);
        float4 a1 = *(const float4*)(xrow + k0 + 4);
        bf16x8 afrag;
        afrag[0] = (short)f2bf(a0.x); afrag[1] = (short)f2bf(a0.y);
        afrag[2] = (short)f2bf(a0.z); afrag[3] = (short)f2bf(a0.w);
        afrag[4] = (short)f2bf(a1.x); afrag[5] = (short)f2bf(a1.y);
        afrag[6] = (short)f2bf(a1.z); afrag[7] = (short)f2bf(a1.w);
#pragma unroll
        for (int t = 0; t < 8; ++t) {
            bf16x8 bfrag = *(const bf16x8*)(Wt + (size_t)(t * 16 + colbase) * D_IN
                                               + k0 + kgrp);
            acc[t] = __builtin_amdgcn_mfma_f32_16x16x32_bf16(afrag, bfrag,
                                                             acc[t], 0, 0, 0);
        }
    }

    int crow = r0 + (lane >> 4) * 4;
    int ccol = lane & 15;
#pragma unroll
    for (int t = 0; t < 8; ++t) {
#pragma unroll
        for (int j = 0; j < 4; ++j)
            support[(size_t)(crow + j) * D_OUT + t * 16 + ccol] = acc[t][j];
    }
}

// ---------------------------------------------------------------------------
// CSR build: zero counts -> histogram -> 3-phase exclusive scan -> permute
// ---------------------------------------------------------------------------
__global__ void zero_counts_kernel(int* __restrict__ counts) {
    int i = blockIdx.x * 256 + threadIdx.x;
    if (i < N_NODES) counts[i] = 0;
}

__global__ void hist_kernel(const int* __restrict__ dst,
                            int* __restrict__ counts) {
    int e = blockIdx.x * 256 + threadIdx.x;
    if (e >= N_EDGES) return;
    atomicAdd(&counts[dst[e]], 1);
}

__global__ void scan1_kernel(const int* __restrict__ counts,
                             int* __restrict__ offsets,
                             int* __restrict__ bsums) {
    __shared__ int tmp[SCAN_BLK];
    int i = blockIdx.x * SCAN_BLK + threadIdx.x;
    int v = (i < N_NODES) ? counts[i] : 0;
    tmp[threadIdx.x] = v;
    __syncthreads();
#pragma unroll
    for (int d = 1; d < SCAN_BLK; d <<= 1) {
        int t = (threadIdx.x >= d) ? tmp[threadIdx.x - d] : 0;
        __syncthreads();
        tmp[threadIdx.x] += t;
        __syncthreads();
    }
    if (i < N_NODES) offsets[i] = tmp[threadIdx.x] - v;   // exclusive
    if (threadIdx.x == SCAN_BLK - 1) bsums[blockIdx.x] = tmp[threadIdx.x];
}

__global__ void scan2_kernel(int* __restrict__ bsums) {
    __shared__ int tmp[512];
    int v = (threadIdx.x < N_SCAN_BLKS) ? bsums[threadIdx.x] : 0;
    tmp[threadIdx.x] = v;
    __syncthreads();
#pragma unroll
    for (int d = 1; d < 512; d <<= 1) {
        int t = ((int)threadIdx.x >= d) ? tmp[threadIdx.x - d] : 0;
        __syncthreads();
        tmp[threadIdx.x] += t;
        __syncthreads();
    }
    if (threadIdx.x < N_SCAN_BLKS) bsums[threadIdx.x] = tmp[threadIdx.x] - v;
}

__global__ void scan3_kernel(int* __restrict__ offsets,
                             const int* __restrict__ bsums) {
    int i = blockIdx.x * SCAN_BLK + threadIdx.x;
    if (i < N_NODES) offsets[i] += bsums[blockIdx.x];
}

// After this kernel, offsets[n] = end of segment n (= start of segment n+1)
__global__ void permute_kernel(const int* __restrict__ src,
                               const int* __restrict__ dst,
                               const float* __restrict__ ew,
                               int* __restrict__ offsets,
                               int2* __restrict__ csr) {
    int e = blockIdx.x * 256 + threadIdx.x;
    if (e >= N_EDGES) return;
    int d = dst[e];
    int pos = atomicAdd(&offsets[d], 1);
    csr[pos] = make_int2(src[e], __float_as_int(ew[e]));
}

// ---------------------------------------------------------------------------
// Gather: one wave per node, lane owns 2 channels (float2).
// out[n] = b + sum_e w_e * support[src_e]
// ---------------------------------------------------------------------------
__global__ __launch_bounds__(256) void gather_kernel(
        const float* __restrict__ support,
        const int2* __restrict__ csr,
        const int* __restrict__ ends,
        const float* __restrict__ b,
        float* __restrict__ out) {
    int wid = (int)((blockIdx.x * blockDim.x + threadIdx.x) >> 6);
    int lane = threadIdx.x & 63;
    if (wid >= N_NODES) return;
    int start = (wid == 0) ? 0 : ends[wid - 1];
    int end = ends[wid];

    const float2* sp = (const float2*)support;
    float2 acc = make_float2(0.f, 0.f);
    int e = start;
    for (; e + 1 < end; e += 2) {
        int2 e0 = csr[e];
        int2 e1 = csr[e + 1];
        float w0 = __int_as_float(e0.y);
        float w1 = __int_as_float(e1.y);
        float2 v0 = sp[(size_t)e0.x * 64 + lane];
        float2 v1 = sp[(size_t)e1.x * 64 + lane];
        acc.x += w0 * v0.x + w1 * v1.x;
        acc.y += w0 * v0.y + w1 * v1.y;
    }
    if (e < end) {
        int2 e0 = csr[e];
        float w0 = __int_as_float(e0.y);
        float2 v0 = sp[(size_t)e0.x * 64 + lane];
        acc.x += w0 * v0.x;
        acc.y += w0 * v0.y;
    }
    float2 bv = ((const float2*)b)[lane];
    ((float2*)out)[(size_t)wid * 64 + lane] =
        make_float2(acc.x + bv.x, acc.y + bv.y);
}

// ---------------------------------------------------------------------------
extern "C" void kernel_launch(void* const* d_in, const int* in_sizes, int n_in,
                              void* d_out, int out_size, void* d_ws, size_t ws_size,
                              hipStream_t stream) {
    const float* x   = (const float*)d_in[0];
    const int* esrc  = (const int*)d_in[1];
    const int* edst  = (const int*)d_in[2];
    const float* ew  = (const float*)d_in[3];
    const float* W   = (const float*)d_in[4];
    const float* b   = (const float*)d_in[5];
    float* out = (float*)d_out;

    // workspace layout (64.9 MB total)
    uint8_t* w8 = (uint8_t*)d_ws;
    float* support      = (float*)w8;                          // 51,200,000 B
    int*   counts       = (int*)(w8 + 51200000);               //    400,000 B
    int*   offsets      = (int*)(w8 + 51600000);               //    400,000 B
    int*   bsums        = (int*)(w8 + 52000000);               //      2,048 B
    int2*  csr          = (int2*)(w8 + 52002048);              // 12,800,000 B
    unsigned short* Wt  = (unsigned short*)(w8 + 64802048);    //     65,536 B

    // --- GEMM path ---
    conv_w_kernel<<<(D_OUT * D_IN + 255) / 256, 256, 0, stream>>>(W, Wt);
    {
        int waves = N_NODES / 16;                 // 6250
        int grid = (waves + 3) / 4;               // 4 waves / block
        gemm_mfma_kernel<<<grid, 256, 0, stream>>>(x, Wt, support);
    }

    // --- CSR build ---
    zero_counts_kernel<<<N_SCAN_BLKS, 256, 0, stream>>>(counts);
    hist_kernel<<<(N_EDGES + 255) / 256, 256, 0, stream>>>(edst, counts);
    scan1_kernel<<<N_SCAN_BLKS, SCAN_BLK, 0, stream>>>(counts, offsets, bsums);
    scan2_kernel<<<1, 512, 0, stream>>>(bsums);
    scan3_kernel<<<N_SCAN_BLKS, SCAN_BLK, 0, stream>>>(offsets, bsums);
    permute_kernel<<<(N_EDGES + 255) / 256, 256, 0, stream>>>(esrc, edst, ew,
                                                              offsets, csr);

    // --- Gather (includes bias) ---
    {
        int grid = (N_NODES + 3) / 4;             // 4 waves / block
        gather_kernel<<<grid, 256, 0, stream>>>(support, csr, offsets, b, out);
    }
}